// Round 9
// baseline (45804.990 us; speedup 1.0000x reference)
//
#include <hip/hip_runtime.h>
#include <hip/hip_cooperative_groups.h>

typedef __bf16 bf16x8 __attribute__((ext_vector_type(8)));
typedef float floatx4 __attribute__((ext_vector_type(4)));
typedef unsigned short u16;
typedef unsigned int u32;

// Sizes: SEQ=256, B=32, NHID=1024, NTOK=32000, NHEADS=4, HD=256
// xi3[32][3072] = [q 0:1024 | attn 1024:2048 | hidden 2048:3072], packed u32 (hi|lo<<16)
// eb[2][32][1024] packed u32, step-parity dbuf. inter[32][4096] packed u32.
// I/O: inputs fp32 (obs int32), output fp32.
// Numerics: recurrence GEMMs via bf16x3 split MFMA (~fp32 accurate); attention/
// LN/softmax fp32; decoder plain bf16 (non-recurrent). Arithmetic order identical
// to round-6/7 -> absmax must be bit-identical (0.00390625).
// Structure: ONE persistent cooperative kernel. All inter-phase data moves via
// relaxed AGENT-scope (sc0/sc1, LLC-coherent) loads/stores -> no stale L2, no
// dirty L2 -> barriers are cheap counter ops (release add on ~clean L2 + poll).

__device__ inline float bf2f(u16 h) { return __uint_as_float(((u32)h) << 16); }
__device__ inline u16 f2bf(float f) {
  u32 u = __float_as_uint(f);
  u += 0x7fffu + ((u >> 16) & 1u);   // RNE
  return (u16)(u >> 16);
}
// packed hi/lo bf16 split of fp32 (hi = bf16(v), lo = bf16(v - hi))
__device__ inline u32 packsplit(float v) {
  u16 h = f2bf(v);
  u16 l = f2bf(v - bf2f(h));
  return (u32)h | ((u32)l << 16);
}

// ---- LLC-coherent (agent-scope, L2-bypass) access helpers ----
__device__ inline u32 ldsc(const u32* p) {
  return __hip_atomic_load(p, __ATOMIC_RELAXED, __HIP_MEMORY_SCOPE_AGENT);
}
__device__ inline float ldscf(const float* p) { return __uint_as_float(ldsc((const u32*)p)); }
__device__ inline void stsc(u32* p, u32 v) {
  __hip_atomic_store(p, v, __ATOMIC_RELAXED, __HIP_MEMORY_SCOPE_AGENT);
}
__device__ inline void stscf(float* p, float v) { stsc((u32*)p, __float_as_uint(v)); }

__device__ inline float wred_add(float v) {
#pragma unroll
  for (int m = 32; m; m >>= 1) v += __shfl_xor(v, m, 64);
  return v;
}
__device__ inline float wred_max(float v) {
#pragma unroll
  for (int m = 32; m; m >>= 1) v = fmaxf(v, __shfl_xor(v, m, 64));
  return v;
}
__device__ inline float bred_add(float v, float* red, int tid) {
  v = wred_add(v);
  if ((tid & 63) == 0) red[tid >> 6] = v;
  __syncthreads();
  v = (red[0] + red[1]) + (red[2] + red[3]) + ((red[4] + red[5]) + (red[6] + red[7]));
  __syncthreads();
  return v;
}
__device__ inline float bred_max(float v, float* red, int tid) {
  v = wred_max(v);
  if ((tid & 63) == 0) red[tid >> 6] = v;
  __syncthreads();
  v = fmaxf(fmaxf(fmaxf(red[0], red[1]), fmaxf(red[2], red[3])),
            fmaxf(fmaxf(red[4], red[5]), fmaxf(red[6], red[7])));
  __syncthreads();
  return v;
}

// ---- grid barrier #k: 8 padded counter cells, monotone targets ----
__device__ inline void gbar(u32* cells, u32 k) {
  __syncthreads();                 // all waves: vmcnt(0) drained
  if (threadIdx.x == 0) {
    __hip_atomic_fetch_add(&cells[(blockIdx.x & 7) << 5], 1u,
                           __ATOMIC_RELEASE, __HIP_MEMORY_SCOPE_AGENT);
    u32 tgt = k * 256u;
    for (;;) {
      u32 s = 0;
#pragma unroll
      for (int c = 0; c < 8; ++c)
        s += __hip_atomic_load(&cells[c << 5], __ATOMIC_RELAXED, __HIP_MEMORY_SCOPE_AGENT);
      if (s >= tgt) break;
      __builtin_amdgcn_s_sleep(8);
    }
  }
  __builtin_amdgcn_fence(__ATOMIC_ACQUIRE, "workgroup");
  __syncthreads();
}

struct Prm {
  const int* obs;
  const float* emb;
  const u16 *qwh, *qwl;
  const float *qb, *qg, *qbt;
  const u16 *iwh, *iwl;
  const float *ib, *ig, *ibt;
  const u16 *fwh, *fwl;
  const float *fb, *fg, *fbt;
  const float *hid0, *key0, *val0;
  u32 *ebp;                 // [2][32][1024]
  u32 *xip;                 // [32][3072]
  u32 *interp;              // [32][4096]
  u16 *states;
  float *keys, *vals;
  float *qpart, *ip1, *ip2, *finpart;
  u32 *cells;
};

// fp32 -> bf16 (n4 = float4 count)
__global__ void cvt_bf16(const float* __restrict__ in, u16* __restrict__ out, int n4) {
  int idx = blockIdx.x * blockDim.x + threadIdx.x;
  int stride = gridDim.x * blockDim.x;
  for (int i = idx; i < n4; i += stride) {
    float4 v = ((const float4*)in)[i];
    ushort4 s;
    s.x = f2bf(v.x); s.y = f2bf(v.y); s.z = f2bf(v.z); s.w = f2bf(v.w);
    ((ushort4*)out)[i] = s;
  }
}
// fp32 -> bf16 hi/lo split (separate arrays, for weights)
__global__ void cvt_split(const float* __restrict__ in, u16* __restrict__ hi,
                          u16* __restrict__ lo, int n4) {
  int idx = blockIdx.x * blockDim.x + threadIdx.x;
  int stride = gridDim.x * blockDim.x;
  for (int i = idx; i < n4; i += stride) {
    float4 v = ((const float4*)in)[i];
    size_t o = (size_t)i * 4;
    u16 h;
    h = f2bf(v.x); hi[o] = h;     lo[o] = f2bf(v.x - bf2f(h));
    h = f2bf(v.y); hi[o + 1] = h; lo[o + 1] = f2bf(v.y - bf2f(h));
    h = f2bf(v.z); hi[o + 2] = h; lo[o + 2] = f2bf(v.z - bf2f(h));
    h = f2bf(v.w); hi[o + 3] = h; lo[o + 3] = f2bf(v.w - bf2f(h));
  }
}

// ---- stage packed A-strip [32][C] into LDS hi/lo (all 512 threads) ----
template <int CLOG>
__device__ inline void stageA(const u32* __restrict__ src, int lda, int col0,
                              u16 (*sh)[520], u16 (*sl)[520], int tid) {
  const int C = 1 << CLOG;
  for (int idx = tid; idx < 32 * C; idx += 512) {
    int r = idx >> CLOG, c = idx & (C - 1);
    u32 v = ldsc(src + (size_t)r * lda + col0 + c);
    sh[r][c] = (u16)(v & 0xffffu);
    sl[r][c] = (u16)(v >> 16);
  }
  __syncthreads();
}

// ---- MFMA from LDS A-strip, global weights (hi*hi + hi*lo + lo*hi) ----
__device__ inline void mm_lds(const u16 (*sh)[520], const u16 (*sl)[520],
                              const u16* __restrict__ Wh, const u16* __restrict__ Wl,
                              int ldw, int wrow0, int wcol0,
                              int nk32, int lane, floatx4& c0, floatx4& c1) {
  const int fr = lane & 15, kg = lane >> 4;
  const size_t woff = (size_t)(wrow0 + fr) * ldw + wcol0 + kg * 8;
  const u16* pwh = Wh + woff;
  const u16* pwl = Wl + woff;
  c0 = floatx4{0.f, 0.f, 0.f, 0.f};
  c1 = floatx4{0.f, 0.f, 0.f, 0.f};
#pragma unroll 4
  for (int t = 0; t < nk32; ++t) {
    int cc = t * 32 + kg * 8;
    bf16x8 ah0 = *(const bf16x8*)&sh[fr][cc];
    bf16x8 ah1 = *(const bf16x8*)&sh[fr + 16][cc];
    bf16x8 al0 = *(const bf16x8*)&sl[fr][cc];
    bf16x8 al1 = *(const bf16x8*)&sl[fr + 16][cc];
    bf16x8 wh  = *(const bf16x8*)pwh;
    bf16x8 wl  = *(const bf16x8*)pwl;
    c0 = __builtin_amdgcn_mfma_f32_16x16x32_bf16(ah0, wh, c0, 0, 0, 0);
    c1 = __builtin_amdgcn_mfma_f32_16x16x32_bf16(ah1, wh, c1, 0, 0, 0);
    c0 = __builtin_amdgcn_mfma_f32_16x16x32_bf16(ah0, wl, c0, 0, 0, 0);
    c1 = __builtin_amdgcn_mfma_f32_16x16x32_bf16(ah1, wl, c1, 0, 0, 0);
    c0 = __builtin_amdgcn_mfma_f32_16x16x32_bf16(al0, wh, c0, 0, 0, 0);
    c1 = __builtin_amdgcn_mfma_f32_16x16x32_bf16(al1, wh, c1, 0, 0, 0);
    pwh += 32; pwl += 32;
  }
}

__device__ inline void store_part_sc(float* outp, int ld, int nt, int lane,
                                     const floatx4& c0, const floatx4& c1) {
  int col = nt * 16 + (lane & 15), kg = lane >> 4;
#pragma unroll
  for (int r = 0; r < 4; ++r) {
    stscf(&outp[(kg * 4 + r) * ld + col], c0[r]);
    stscf(&outp[(kg * 4 + r + 16) * ld + col], c1[r]);
  }
}

// ---------------- persistent recurrence kernel (256 blk x 512 thr) ----------------
__global__ void __launch_bounds__(512, 1) rnn_kernel(Prm p) {
  __shared__ u16 sAh[32][520];
  __shared__ u16 sAl[32][520];
  __shared__ float sm[2080];
  float* qrow = sm;            // 1024
  float* qn   = sm + 1024;     // 256
  float* sc   = sm + 1280;     // 257
  float* pv   = sm + 1544;     // 512
  float* red  = sm + 2056;     // 8
  const int blk = blockIdx.x, tid = threadIdx.x;
  const int lane = tid & 63, wv = tid >> 6;
  u32* cells = p.cells;
  u32 k = 0;

  // ---- init: emb step 0 -> eb[0], hidden0 -> xi.hidden; KV slot 0 ----
  if (blk < 32) {
    int b = blk;
    if (tid < 256) {
      int tok = p.obs[b];
      float4 e4 = ((const float4*)(p.emb + (size_t)tok * 1024))[tid];
      size_t o = (size_t)b * 1024 + 4 * tid;
      stsc(&p.ebp[o], packsplit(e4.x));     stsc(&p.ebp[o + 1], packsplit(e4.y));
      stsc(&p.ebp[o + 2], packsplit(e4.z)); stsc(&p.ebp[o + 3], packsplit(e4.w));
      float4 h4 = ((const float4*)(p.hid0 + (size_t)b * 1024))[tid];
      size_t x = (size_t)b * 3072 + 2048 + 4 * tid;
      stsc(&p.xip[x], packsplit(h4.x));     stsc(&p.xip[x + 1], packsplit(h4.y));
      stsc(&p.xip[x + 2], packsplit(h4.z)); stsc(&p.xip[x + 3], packsplit(h4.w));
    }
  } else if (blk < 64) {
    int b = blk - 32;
    for (int e = tid; e < 1024; e += 512) {
      stscf(&p.keys[(size_t)b * 1024 + e], p.key0[(size_t)b * 1024 + e]);
      stscf(&p.vals[(size_t)b * 1024 + e], p.val0[(size_t)b * 1024 + e]);
    }
  }
  gbar(cells, ++k);

  for (int i = 0; i < 256; ++i) {
    const size_t ecur = (size_t)(i & 1) * 32768;
    const size_t enxt = (size_t)((i + 1) & 1) * 32768;

    // ---- P1: q (blk<64) || int1 (64..191) || emb gather i+1 (192..223) ----
    if (blk < 64) {
      int kc = blk >> 3;               // 0..7, K-chunk 256
      if (kc < 4) stageA<8>(p.ebp + ecur, 1024, kc * 256, sAh, sAl, tid);
      else        stageA<8>(p.xip, 3072, 2048 + (kc - 4) * 256, sAh, sAl, tid);
      int nt = (blk & 7) * 8 + wv;     // 0..63
      int wcol = (kc < 4) ? kc * 256 : 1024 + (kc - 4) * 256;
      floatx4 c0, c1;
      mm_lds(sAh, sAl, p.qwh, p.qwl, 2048, nt * 16, wcol, 8, lane, c0, c1);
      store_part_sc(p.qpart + (size_t)kc * 32 * 1024, 1024, nt, lane, c0, c1);
    } else if (blk < 192) {
      int b2 = blk - 64;
      int kc = b2 >> 5;                // 0..3, K-chunk 512
      if (kc < 2) stageA<9>(p.ebp + ecur, 1024, kc * 512, sAh, sAl, tid);
      else        stageA<9>(p.xip, 3072, 2048 + (kc - 2) * 512, sAh, sAl, tid);
      int nt = (b2 & 31) * 8 + wv;     // 0..255
      int wcol = (kc < 2) ? kc * 512 : 3072 + (kc - 2) * 512;
      floatx4 c0, c1;
      mm_lds(sAh, sAl, p.iwh, p.iwl, 4096, nt * 16, wcol, 16, lane, c0, c1);
      store_part_sc(p.ip1 + (size_t)kc * 32 * 4096, 4096, nt, lane, c0, c1);
    } else if (blk < 224) {
      if (i + 1 < 256 && tid < 256) {
        int b = blk - 192;
        int tok = p.obs[(i + 1) * 32 + b];
        float4 e4 = ((const float4*)(p.emb + (size_t)tok * 1024))[tid];
        size_t o = enxt + (size_t)b * 1024 + 4 * tid;
        stsc(&p.ebp[o], packsplit(e4.x));     stsc(&p.ebp[o + 1], packsplit(e4.y));
        stsc(&p.ebp[o + 2], packsplit(e4.z)); stsc(&p.ebp[o + 3], packsplit(e4.w));
      }
    }
    gbar(cells, ++k);

    // ---- P2: attention (+ LN-q), blocks 0..127 ----
    if (blk < 128) {
      int b = blk >> 2, h = blk & 3;
      float s1 = 0.f, s2 = 0.f;
      for (int e = tid; e < 1024; e += 512) {
        size_t o = (size_t)b * 1024 + e;
        float v = ((ldscf(&p.qpart[o]) + ldscf(&p.qpart[32768 + o])) +
                   (ldscf(&p.qpart[65536 + o]) + ldscf(&p.qpart[98304 + o]))) +
                  ((ldscf(&p.qpart[131072 + o]) + ldscf(&p.qpart[163840 + o])) +
                   (ldscf(&p.qpart[196608 + o]) + ldscf(&p.qpart[229376 + o]))) + p.qb[e];
        qrow[e] = v; s1 += v; s2 += v * v;
      }
      __syncthreads();
      s1 = bred_add(s1, red, tid);
      s2 = bred_add(s2, red, tid);
      float mu = s1 * (1.f / 1024.f);
      float rs = rsqrtf(s2 * (1.f / 1024.f) - mu * mu + 1e-5f);
      if (tid < 256) {
        int e = h * 256 + tid;
        float y = fmaxf((qrow[e] - mu) * rs * p.qg[e] + p.qbt[e], 0.f);
        qn[tid] = y;
        stsc(&p.xip[(size_t)b * 3072 + e], packsplit(y));
      }
      __syncthreads();
      // scores over slots 0..i; scale = 1/(16*0.1) = 0.625
      for (int s = wv; s <= i; s += 8) {
        const float* kp = p.keys + ((size_t)s * 32 + b) * 1024 + h * 256 + lane * 4;
        float kx = ldscf(kp), ky = ldscf(kp + 1), kz = ldscf(kp + 2), kw = ldscf(kp + 3);
        float pd = qn[lane * 4] * kx + qn[lane * 4 + 1] * ky +
                   qn[lane * 4 + 2] * kz + qn[lane * 4 + 3] * kw;
        pd = wred_add(pd);
        if (lane == 0) sc[s] = pd * 0.625f;
      }
      __syncthreads();
      float mx = (tid <= i) ? sc[tid] : -1e30f;
      mx = bred_max(mx, red, tid);
      float sum = 0.f;
      if (tid <= i) { float e = expf(sc[tid] - mx); sc[tid] = e; sum = e; }
      sum = bred_add(sum, red, tid);
      float inv = 1.f / sum;
      {
        float acc = 0.f;
        int d = tid & 255, half = tid >> 8;
        const float* vp = p.vals + (size_t)b * 1024 + h * 256 + d;
#pragma unroll 4
        for (int s = half; s <= i; s += 2) acc += sc[s] * ldscf(vp + (size_t)s * 32768);
        pv[tid] = acc;
      }
      __syncthreads();
      if (tid < 256) {
        float val = (pv[tid] + pv[tid + 256]) * inv;
        stsc(&p.xip[(size_t)b * 3072 + 1024 + h * 256 + tid], packsplit(val));
      }
    }
    gbar(cells, ++k);

    // ---- P3: int2 (q+attn half), all 256 blocks ----
    {
      int kc = blk >> 5;               // 0..7, K-chunk 256
      stageA<8>(p.xip, 3072, kc * 256, sAh, sAl, tid);
      int nt = (blk & 31) * 8 + wv;    // 0..255
      floatx4 c0, c1;
      mm_lds(sAh, sAl, p.iwh, p.iwl, 4096, nt * 16, 1024 + kc * 256, 8, lane, c0, c1);
      store_part_sc(p.ip2 + (size_t)kc * 32 * 4096, 4096, nt, lane, c0, c1);
    }
    gbar(cells, ++k);

    // ---- P4: LN-int (blocks 0..31) ----
    if (blk < 32) {
      int b = blk;
      float xs[8], s1 = 0.f, s2 = 0.f;
#pragma unroll
      for (int j = 0; j < 8; ++j) {
        int e = tid + j * 512;
        size_t o = (size_t)b * 4096 + e;
        float x = ((ldscf(&p.ip1[o]) + ldscf(&p.ip1[131072 + o])) +
                   (ldscf(&p.ip1[262144 + o]) + ldscf(&p.ip1[393216 + o]))) +
                  ((ldscf(&p.ip2[o]) + ldscf(&p.ip2[131072 + o])) +
                   (ldscf(&p.ip2[262144 + o]) + ldscf(&p.ip2[393216 + o]))) +
                  ((ldscf(&p.ip2[524288 + o]) + ldscf(&p.ip2[655360 + o])) +
                   (ldscf(&p.ip2[786432 + o]) + ldscf(&p.ip2[917504 + o]))) + p.ib[e];
        xs[j] = x; s1 += x; s2 += x * x;
      }
      s1 = bred_add(s1, red, tid);
      s2 = bred_add(s2, red, tid);
      float mu = s1 * (1.f / 4096.f);
      float rs = rsqrtf(s2 * (1.f / 4096.f) - mu * mu + 1e-5f);
#pragma unroll
      for (int j = 0; j < 8; ++j) {
        int e = tid + j * 512;
        float y = fmaxf((xs[j] - mu) * rs * p.ig[e] + p.ibt[e], 0.f);
        stsc(&p.interp[(size_t)b * 4096 + e], packsplit(y));
      }
    }
    gbar(cells, ++k);

    // ---- P5: fin-GEMM (1536 wave-tasks over all 256 blocks, wv<6) ----
    {
      int kc = blk >> 5;               // 0..7, K-chunk 512
      stageA<9>(p.interp, 4096, kc * 512, sAh, sAl, tid);
      if (wv < 6) {
        int nt = (blk & 31) * 6 + wv;  // 0..191
        floatx4 c0, c1;
        mm_lds(sAh, sAl, p.fwh, p.fwl, 4096, nt * 16, kc * 512, 16, lane, c0, c1);
        store_part_sc(p.finpart + (size_t)kc * 32 * 3072, 3072, nt, lane, c0, c1);
      }
    }
    gbar(cells, ++k);

    // ---- P6: merge fin + LN; keys/vals slot i+1, hidden -> xi & states ----
    if (blk < 32) {
      int b = blk;
      float xs[6], s1 = 0.f, s2 = 0.f;
#pragma unroll
      for (int j = 0; j < 6; ++j) {
        int e = tid + j * 512;
        size_t o = (size_t)b * 3072 + e;
        float x = ((ldscf(&p.finpart[o]) + ldscf(&p.finpart[98304 + o])) +
                   (ldscf(&p.finpart[196608 + o]) + ldscf(&p.finpart[294912 + o]))) +
                  ((ldscf(&p.finpart[393216 + o]) + ldscf(&p.finpart[491520 + o])) +
                   (ldscf(&p.finpart[589824 + o]) + ldscf(&p.finpart[688128 + o]))) + p.fb[e];
        xs[j] = x; s1 += x; s2 += x * x;
      }
      s1 = bred_add(s1, red, tid);
      s2 = bred_add(s2, red, tid);
      float mu = s1 * (1.f / 3072.f);
      float rs = rsqrtf(s2 * (1.f / 3072.f) - mu * mu + 1e-5f);
#pragma unroll
      for (int j = 0; j < 6; ++j) {
        int e = tid + j * 512;
        float y = fmaxf((xs[j] - mu) * rs * p.fg[e] + p.fbt[e], 0.f);
        if (j < 2) {
          stscf(&p.keys[((size_t)(i + 1) * 32 + b) * 1024 + e], y);
        } else if (j < 4) {
          stscf(&p.vals[((size_t)(i + 1) * 32 + b) * 1024 + (e - 1024)], y);
        } else {
          int d = e - 2048;
          stsc(&p.xip[(size_t)b * 3072 + 2048 + d], packsplit(y));
          p.states[((size_t)i * 32 + b) * 1024 + d] = f2bf(y);  // normal store; read post-boundary
        }
      }
    }
    gbar(cells, ++k);
  }
}

// ---------------- decoder GEMM: logits = states @ dec_w^T + dec_b ----------------
__global__ void __launch_bounds__(256) dec_gemm(const u16* __restrict__ Sm,
                                                const u16* __restrict__ W,
                                                const float* __restrict__ Wb,
                                                float* __restrict__ out) {
  __shared__ u16 As[2][128 * 40];
  __shared__ u16 Bs[2][128 * 40];
  int bid = blockIdx.x;                      // 16000 % 8 == 0
  int swz = (bid & 7) * 2000 + (bid >> 3);
  int mt = swz / 250, nt = swz - mt * 250;
  const int tid = threadIdx.x;
  const int lane = tid & 63, wvi = tid >> 6;
  const int wm = wvi >> 1, wn = wvi & 1;
  const int fr = lane & 15, fg = lane >> 4;

  const int r0 = tid >> 2, k0 = (tid & 3) * 8;
  const u16* pa0 = Sm + (size_t)(mt * 128 + r0) * 1024 + k0;
  const u16* pa1 = pa0 + (size_t)64 * 1024;
  const u16* pb0 = W + (size_t)(nt * 128 + r0) * 1024 + k0;
  const u16* pb1 = pb0 + (size_t)64 * 1024;
  const int da0 = r0 * 40 + k0, da1 = (r0 + 64) * 40 + k0;

  floatx4 acc[4][4];
#pragma unroll
  for (int i = 0; i < 4; ++i)
#pragma unroll
    for (int j = 0; j < 4; ++j) acc[i][j] = floatx4{0.f, 0.f, 0.f, 0.f};

  uint4 ra0 = *(const uint4*)pa0, ra1 = *(const uint4*)pa1;
  uint4 rb0 = *(const uint4*)pb0, rb1 = *(const uint4*)pb1;
  *(uint4*)&As[0][da0] = ra0; *(uint4*)&As[0][da1] = ra1;
  *(uint4*)&Bs[0][da0] = rb0; *(uint4*)&Bs[0][da1] = rb1;
  __syncthreads();

  for (int kt = 0; kt < 32; ++kt) {
    const int cur = kt & 1;
    if (kt < 31) {
      const int off = (kt + 1) * 32;
      ra0 = *(const uint4*)(pa0 + off); ra1 = *(const uint4*)(pa1 + off);
      rb0 = *(const uint4*)(pb0 + off); rb1 = *(const uint4*)(pb1 + off);
    }
    bf16x8 af[4], bfv[4];
#pragma unroll
    for (int i = 0; i < 4; ++i) {
      af[i]  = *(const bf16x8*)&As[cur][(wm * 64 + i * 16 + fr) * 40 + fg * 8];
      bfv[i] = *(const bf16x8*)&Bs[cur][(wn * 64 + i * 16 + fr) * 40 + fg * 8];
    }
#pragma unroll
    for (int i = 0; i < 4; ++i)
#pragma unroll
      for (int j = 0; j < 4; ++j)
        acc[i][j] = __builtin_amdgcn_mfma_f32_16x16x32_bf16(af[i], bfv[j], acc[i][j], 0, 0, 0);
    if (kt < 31) {
      *(uint4*)&As[cur ^ 1][da0] = ra0; *(uint4*)&As[cur ^ 1][da1] = ra1;
      *(uint4*)&Bs[cur ^ 1][da0] = rb0; *(uint4*)&Bs[cur ^ 1][da1] = rb1;
    }
    __syncthreads();
  }

#pragma unroll
  for (int i = 0; i < 4; ++i)
#pragma unroll
    for (int j = 0; j < 4; ++j) {
      int col = nt * 128 + wn * 64 + j * 16 + fr;
      float bias = Wb[col];
#pragma unroll
      for (int r = 0; r < 4; ++r) {
        int row = mt * 128 + wm * 64 + i * 16 + fg * 4 + r;
        out[(size_t)row * 32000 + col] = acc[i][j][r] + bias;
      }
    }
}

extern "C" void kernel_launch(void* const* d_in, const int* in_sizes, int n_in,
                              void* d_out, int out_size, void* d_ws, size_t ws_size,
                              hipStream_t stream) {
  (void)in_sizes; (void)n_in; (void)out_size; (void)ws_size;
  char* ws = (char*)d_ws;
  size_t off = 0;
  auto carve = [&](size_t bytes) {
    void* pp = ws + off;
    off += (bytes + 255) & ~(size_t)255;
    return pp;
  };
  u16* qwh       = (u16*)carve((size_t)1024 * 2048 * 2);
  u16* qwl       = (u16*)carve((size_t)1024 * 2048 * 2);
  u16* iwh       = (u16*)carve((size_t)4096 * 4096 * 2);
  u16* iwl       = (u16*)carve((size_t)4096 * 4096 * 2);
  u16* fwh       = (u16*)carve((size_t)3072 * 4096 * 2);
  u16* fwl       = (u16*)carve((size_t)3072 * 4096 * 2);
  u32* ebp       = (u32*)carve((size_t)2 * 32 * 1024 * 4);
  u32* xip       = (u32*)carve((size_t)32 * 3072 * 4);
  u32* interp    = (u32*)carve((size_t)32 * 4096 * 4);
  float* qpart   = (float*)carve((size_t)8 * 32 * 1024 * 4);
  float* ip1     = (float*)carve((size_t)4 * 32 * 4096 * 4);
  float* ip2     = (float*)carve((size_t)8 * 32 * 4096 * 4);
  float* finpart = (float*)carve((size_t)8 * 32 * 3072 * 4);
  float* keysF   = (float*)carve((size_t)257 * 32 * 1024 * 4);
  float* valsF   = (float*)carve((size_t)257 * 32 * 1024 * 4);
  u16* states    = (u16*)carve((size_t)256 * 32 * 1024 * 2);
  u32* cells     = (u32*)carve((size_t)1024);
  // dec_w bf16 reuses the then-dead q/int weight region after the RNN.
  u16* dw_bf = (u16*)ws;

  hipMemsetAsync(cells, 0, 1024, stream);

  // weight hi/lo splits
  cvt_split<<<dim3(512), dim3(256), 0, stream>>>((const float*)d_in[2], qwh, qwl, 1024 * 2048 / 4);
  cvt_split<<<dim3(2048), dim3(256), 0, stream>>>((const float*)d_in[6], iwh, iwl, 4096 * 4096 / 4);
  cvt_split<<<dim3(2048), dim3(256), 0, stream>>>((const float*)d_in[10], fwh, fwl, 3072 * 4096 / 4);

  Prm prm;
  prm.obs = (const int*)d_in[0];
  prm.emb = (const float*)d_in[1];
  prm.qwh = qwh; prm.qwl = qwl;
  prm.qb  = (const float*)d_in[3];
  prm.qg  = (const float*)d_in[4];
  prm.qbt = (const float*)d_in[5];
  prm.iwh = iwh; prm.iwl = iwl;
  prm.ib  = (const float*)d_in[7];
  prm.ig  = (const float*)d_in[8];
  prm.ibt = (const float*)d_in[9];
  prm.fwh = fwh; prm.fwl = fwl;
  prm.fb  = (const float*)d_in[11];
  prm.fg  = (const float*)d_in[12];
  prm.fbt = (const float*)d_in[13];
  prm.hid0 = (const float*)d_in[16];
  prm.key0 = (const float*)d_in[17];
  prm.val0 = (const float*)d_in[18];
  prm.ebp = ebp; prm.xip = xip; prm.interp = interp;
  prm.states = states; prm.keys = keysF; prm.vals = valsF;
  prm.qpart = qpart; prm.ip1 = ip1; prm.ip2 = ip2; prm.finpart = finpart;
  prm.cells = cells;

  void* args[] = { &prm };
  hipLaunchCooperativeKernel(rnn_kernel, dim3(256), dim3(512), args, 0, stream);

  // dec_w fp32 -> bf16 into reused region (q/int weights dead after RNN)
  cvt_bf16<<<dim3(4096), dim3(256), 0, stream>>>((const float*)d_in[14], dw_bf, 32000 * 1024 / 4);

  dec_gemm<<<dim3(16000), dim3(256), 0, stream>>>(
      states, dw_bf, (const float*)d_in[15], (float*)d_out);
}

// Round 10
// 40692.862 us; speedup vs baseline: 1.1256x; 1.1256x over previous
//
#include <hip/hip_runtime.h>
#include <hip/hip_cooperative_groups.h>

typedef __bf16 bf16x8 __attribute__((ext_vector_type(8)));
typedef float floatx4 __attribute__((ext_vector_type(4)));
typedef unsigned short u16;
typedef unsigned int u32;

// Sizes: SEQ=256, B=32, NHID=1024, NTOK=32000, NHEADS=4, HD=256
// xi3[32][3072] = [q | attn | hidden] packed u32 (hi|lo<<16); eb[2][32][1024] packed;
// inter[32][4096] packed. I/O: inputs fp32 (obs int32), output fp32.
// Numerics: recurrence GEMMs via bf16x3 split MFMA (~fp32); attention/LN/softmax fp32;
// decoder plain bf16. Arithmetic identical to r9 -> absmax must stay 0.00390625.
// Sync: per-block monotone phase flags (relaxed sc stores, NO RMW/NO wbl2) +
// wave-parallel min-polls with targeted producer sets. Data path: all inter-phase
// traffic via relaxed AGENT-scope (sc0/sc1, LLC-coherent) accesses as in r9.

__device__ inline float bf2f(u16 h) { return __uint_as_float(((u32)h) << 16); }
__device__ inline u16 f2bf(float f) {
  u32 u = __float_as_uint(f);
  u += 0x7fffu + ((u >> 16) & 1u);   // RNE
  return (u16)(u >> 16);
}
__device__ inline u32 packsplit(float v) {
  u16 h = f2bf(v);
  u16 l = f2bf(v - bf2f(h));
  return (u32)h | ((u32)l << 16);
}

// ---- LLC-coherent (agent-scope, L2-bypass) access helpers ----
__device__ inline u32 ldsc(const u32* p) {
  return __hip_atomic_load(p, __ATOMIC_RELAXED, __HIP_MEMORY_SCOPE_AGENT);
}
__device__ inline float ldscf(const float* p) { return __uint_as_float(ldsc((const u32*)p)); }
__device__ inline void stsc(u32* p, u32 v) {
  __hip_atomic_store(p, v, __ATOMIC_RELAXED, __HIP_MEMORY_SCOPE_AGENT);
}
__device__ inline void stscf(float* p, float v) { stsc((u32*)p, __float_as_uint(v)); }

__device__ inline float wred_add(float v) {
#pragma unroll
  for (int m = 32; m; m >>= 1) v += __shfl_xor(v, m, 64);
  return v;
}
__device__ inline float wred_max(float v) {
#pragma unroll
  for (int m = 32; m; m >>= 1) v = fmaxf(v, __shfl_xor(v, m, 64));
  return v;
}
__device__ inline u32 wred_minu(u32 v) {
#pragma unroll
  for (int m = 32; m; m >>= 1) {
    u32 o = (u32)__shfl_xor((int)v, m, 64);
    v = (o < v) ? o : v;
  }
  return v;
}
__device__ inline float bred_add(float v, float* red, int tid) {
  v = wred_add(v);
  if ((tid & 63) == 0) red[tid >> 6] = v;
  __syncthreads();
  v = (red[0] + red[1]) + (red[2] + red[3]) + ((red[4] + red[5]) + (red[6] + red[7]));
  __syncthreads();
  return v;
}
__device__ inline float bred_max(float v, float* red, int tid) {
  v = wred_max(v);
  if ((tid & 63) == 0) red[tid >> 6] = v;
  __syncthreads();
  v = fmaxf(fmaxf(fmaxf(red[0], red[1]), fmaxf(red[2], red[3])),
            fmaxf(fmaxf(red[4], red[5]), fmaxf(red[6], red[7])));
  __syncthreads();
  return v;
}

// ---- targeted flag wait: block proceeds when subset minima reach targets ----
// t31: min over blocks 0..31; t63: 0..63; t127: 0..127; tall: 0..255. 0 = skip.
__device__ inline void gwait(u32* flags, u32 t31, u32 t63, u32 t127, u32 tall) {
  if (threadIdx.x < 64) {
    const int l = threadIdx.x;
    for (;;) {
      u32 v0 = ldsc(&flags[l]);
      u32 v1 = ldsc(&flags[l + 64]);
      u32 v2 = ldsc(&flags[l + 128]);
      u32 v3 = ldsc(&flags[l + 192]);
      u32 m31 = wred_minu(l < 32 ? v0 : 0xffffffffu);
      u32 m63 = wred_minu(v0);
      u32 a = (v1 < v0) ? v1 : v0;
      u32 m127 = wred_minu(a);
      u32 b = (v3 < v2) ? v3 : v2;
      u32 mall = wred_minu((b < a) ? b : a);
      if (m31 >= t31 && m63 >= t63 && m127 >= t127 && mall >= tall) break;
      __builtin_amdgcn_s_sleep(16);
    }
  }
  __syncthreads();
}
// ---- phase bump: all block stores retired (syncthreads -> vmcnt(0)), then
// fire-and-forget relaxed sc store of monotone counter. No RMW, no wbl2. ----
__device__ inline void gpost(u32* flags, int blk, u32 val) {
  __syncthreads();
  if (threadIdx.x == 0) stsc(&flags[blk], val);
}

struct Prm {
  const int* obs;
  const float* emb;
  const u16 *qwh, *qwl;
  const float *qb, *qg, *qbt;
  const u16 *iwh, *iwl;
  const float *ib, *ig, *ibt;
  const u16 *fwh, *fwl;
  const float *fb, *fg, *fbt;
  const float *hid0, *key0, *val0;
  u32 *ebp;                 // [2][32][1024]
  u32 *xip;                 // [32][3072]
  u32 *interp;              // [32][4096]
  u16 *states;
  float *keys, *vals;
  float *qpart, *ip1, *ip2, *finpart;
  u32 *flags;
};

__global__ void cvt_bf16(const float* __restrict__ in, u16* __restrict__ out, int n4) {
  int idx = blockIdx.x * blockDim.x + threadIdx.x;
  int stride = gridDim.x * blockDim.x;
  for (int i = idx; i < n4; i += stride) {
    float4 v = ((const float4*)in)[i];
    ushort4 s;
    s.x = f2bf(v.x); s.y = f2bf(v.y); s.z = f2bf(v.z); s.w = f2bf(v.w);
    ((ushort4*)out)[i] = s;
  }
}
__global__ void cvt_split(const float* __restrict__ in, u16* __restrict__ hi,
                          u16* __restrict__ lo, int n4) {
  int idx = blockIdx.x * blockDim.x + threadIdx.x;
  int stride = gridDim.x * blockDim.x;
  for (int i = idx; i < n4; i += stride) {
    float4 v = ((const float4*)in)[i];
    size_t o = (size_t)i * 4;
    u16 h;
    h = f2bf(v.x); hi[o] = h;     lo[o] = f2bf(v.x - bf2f(h));
    h = f2bf(v.y); hi[o + 1] = h; lo[o + 1] = f2bf(v.y - bf2f(h));
    h = f2bf(v.z); hi[o + 2] = h; lo[o + 2] = f2bf(v.z - bf2f(h));
    h = f2bf(v.w); hi[o + 3] = h; lo[o + 3] = f2bf(v.w - bf2f(h));
  }
}

// ---- stage packed A-strip [32][C] into LDS hi/lo (all 512 threads) ----
template <int CLOG>
__device__ inline void stageA(const u32* __restrict__ src, int lda, int col0,
                              u16 (*sh)[520], u16 (*sl)[520], int tid) {
  const int C = 1 << CLOG;
  for (int idx = tid; idx < 32 * C; idx += 512) {
    int r = idx >> CLOG, c = idx & (C - 1);
    u32 v = ldsc(src + (size_t)r * lda + col0 + c);
    sh[r][c] = (u16)(v & 0xffffu);
    sl[r][c] = (u16)(v >> 16);
  }
  __syncthreads();
}

// ---- MFMA from LDS A-strip, global weights (hi*hi + hi*lo + lo*hi) ----
__device__ inline void mm_lds(const u16 (*sh)[520], const u16 (*sl)[520],
                              const u16* __restrict__ Wh, const u16* __restrict__ Wl,
                              int ldw, int wrow0, int wcol0,
                              int nk32, int lane, floatx4& c0, floatx4& c1) {
  const int fr = lane & 15, kg = lane >> 4;
  const size_t woff = (size_t)(wrow0 + fr) * ldw + wcol0 + kg * 8;
  const u16* pwh = Wh + woff;
  const u16* pwl = Wl + woff;
  c0 = floatx4{0.f, 0.f, 0.f, 0.f};
  c1 = floatx4{0.f, 0.f, 0.f, 0.f};
#pragma unroll 4
  for (int t = 0; t < nk32; ++t) {
    int cc = t * 32 + kg * 8;
    bf16x8 ah0 = *(const bf16x8*)&sh[fr][cc];
    bf16x8 ah1 = *(const bf16x8*)&sh[fr + 16][cc];
    bf16x8 al0 = *(const bf16x8*)&sl[fr][cc];
    bf16x8 al1 = *(const bf16x8*)&sl[fr + 16][cc];
    bf16x8 wh  = *(const bf16x8*)pwh;
    bf16x8 wl  = *(const bf16x8*)pwl;
    c0 = __builtin_amdgcn_mfma_f32_16x16x32_bf16(ah0, wh, c0, 0, 0, 0);
    c1 = __builtin_amdgcn_mfma_f32_16x16x32_bf16(ah1, wh, c1, 0, 0, 0);
    c0 = __builtin_amdgcn_mfma_f32_16x16x32_bf16(ah0, wl, c0, 0, 0, 0);
    c1 = __builtin_amdgcn_mfma_f32_16x16x32_bf16(ah1, wl, c1, 0, 0, 0);
    c0 = __builtin_amdgcn_mfma_f32_16x16x32_bf16(al0, wh, c0, 0, 0, 0);
    c1 = __builtin_amdgcn_mfma_f32_16x16x32_bf16(al1, wh, c1, 0, 0, 0);
    pwh += 32; pwl += 32;
  }
}

__device__ inline void store_part_sc(float* outp, int ld, int nt, int lane,
                                     const floatx4& c0, const floatx4& c1) {
  int col = nt * 16 + (lane & 15), kg = lane >> 4;
#pragma unroll
  for (int r = 0; r < 4; ++r) {
    stscf(&outp[(kg * 4 + r) * ld + col], c0[r]);
    stscf(&outp[(kg * 4 + r + 16) * ld + col], c1[r]);
  }
}

// ---------------- persistent recurrence kernel (256 blk x 512 thr) ----------------
__global__ void __launch_bounds__(512, 1) rnn_kernel(Prm p) {
  __shared__ u16 sAh[32][520];
  __shared__ u16 sAl[32][520];
  __shared__ float sm[2080];
  float* qrow = sm;            // 1024
  float* qn   = sm + 1024;     // 256
  float* sc   = sm + 1280;     // 257
  float* pv   = sm + 1544;     // 512
  float* red  = sm + 2056;     // 8
  const int blk = blockIdx.x, tid = threadIdx.x;
  const int lane = tid & 63, wv = tid >> 6;
  u32* flags = p.flags;

  // ---- init: emb step 0 -> eb[0], hidden0 -> xi.hidden; KV slot 0 ----
  if (blk < 32) {
    int b = blk;
    if (tid < 256) {
      int tok = p.obs[b];
      float4 e4 = ((const float4*)(p.emb + (size_t)tok * 1024))[tid];
      size_t o = (size_t)b * 1024 + 4 * tid;
      stsc(&p.ebp[o], packsplit(e4.x));     stsc(&p.ebp[o + 1], packsplit(e4.y));
      stsc(&p.ebp[o + 2], packsplit(e4.z)); stsc(&p.ebp[o + 3], packsplit(e4.w));
      float4 h4 = ((const float4*)(p.hid0 + (size_t)b * 1024))[tid];
      size_t x = (size_t)b * 3072 + 2048 + 4 * tid;
      stsc(&p.xip[x], packsplit(h4.x));     stsc(&p.xip[x + 1], packsplit(h4.y));
      stsc(&p.xip[x + 2], packsplit(h4.z)); stsc(&p.xip[x + 3], packsplit(h4.w));
    }
  } else if (blk < 64) {
    int b = blk - 32;
    for (int e = tid; e < 1024; e += 512) {
      stscf(&p.keys[(size_t)b * 1024 + e], p.key0[(size_t)b * 1024 + e]);
      stscf(&p.vals[(size_t)b * 1024 + e], p.val0[(size_t)b * 1024 + e]);
    }
  }
  gpost(flags, blk, 1u);

  for (int i = 0; i < 256; ++i) {
    const size_t ecur = (size_t)(i & 1) * 32768;
    const size_t enxt = (size_t)((i + 1) & 1) * 32768;
    const u32 base = 6u * (u32)i;

    // ---- P1: q (blk<64) || int1 (64..191) || emb gather i+1 (192..223) ----
    if (blk < 224) {
      gwait(flags, base + 1u, 0, 0, i ? base - 4u : 0);
      if (blk < 64) {
        int kc = blk >> 3;               // 0..7, K-chunk 256
        if (kc < 4) stageA<8>(p.ebp + ecur, 1024, kc * 256, sAh, sAl, tid);
        else        stageA<8>(p.xip, 3072, 2048 + (kc - 4) * 256, sAh, sAl, tid);
        int nt = (blk & 7) * 8 + wv;     // 0..63
        int wcol = (kc < 4) ? kc * 256 : 1024 + (kc - 4) * 256;
        floatx4 c0, c1;
        mm_lds(sAh, sAl, p.qwh, p.qwl, 2048, nt * 16, wcol, 8, lane, c0, c1);
        store_part_sc(p.qpart + (size_t)kc * 32 * 1024, 1024, nt, lane, c0, c1);
      } else if (blk < 192) {
        int b2 = blk - 64;
        int kc = b2 >> 5;                // 0..3, K-chunk 512
        if (kc < 2) stageA<9>(p.ebp + ecur, 1024, kc * 512, sAh, sAl, tid);
        else        stageA<9>(p.xip, 3072, 2048 + (kc - 2) * 512, sAh, sAl, tid);
        int nt = (b2 & 31) * 8 + wv;     // 0..255
        int wcol = (kc < 2) ? kc * 512 : 3072 + (kc - 2) * 512;
        floatx4 c0, c1;
        mm_lds(sAh, sAl, p.iwh, p.iwl, 4096, nt * 16, wcol, 16, lane, c0, c1);
        store_part_sc(p.ip1 + (size_t)kc * 32 * 4096, 4096, nt, lane, c0, c1);
      } else {
        if (i + 1 < 256 && tid < 256) {
          int b = blk - 192;
          int tok = p.obs[(i + 1) * 32 + b];
          float4 e4 = ((const float4*)(p.emb + (size_t)tok * 1024))[tid];
          size_t o = enxt + (size_t)b * 1024 + 4 * tid;
          stsc(&p.ebp[o], packsplit(e4.x));     stsc(&p.ebp[o + 1], packsplit(e4.y));
          stsc(&p.ebp[o + 2], packsplit(e4.z)); stsc(&p.ebp[o + 3], packsplit(e4.w));
        }
      }
    }
    gpost(flags, blk, base + 2u);

    // ---- P2: attention (+ LN-q), blocks 0..127 ----
    if (blk < 128) {
      gwait(flags, 0, base + 2u, 0, 0);
      int b = blk >> 2, h = blk & 3;
      float s1 = 0.f, s2 = 0.f;
      for (int e = tid; e < 1024; e += 512) {
        size_t o = (size_t)b * 1024 + e;
        float v = ((ldscf(&p.qpart[o]) + ldscf(&p.qpart[32768 + o])) +
                   (ldscf(&p.qpart[65536 + o]) + ldscf(&p.qpart[98304 + o]))) +
                  ((ldscf(&p.qpart[131072 + o]) + ldscf(&p.qpart[163840 + o])) +
                   (ldscf(&p.qpart[196608 + o]) + ldscf(&p.qpart[229376 + o]))) + p.qb[e];
        qrow[e] = v; s1 += v; s2 += v * v;
      }
      __syncthreads();
      s1 = bred_add(s1, red, tid);
      s2 = bred_add(s2, red, tid);
      float mu = s1 * (1.f / 1024.f);
      float rs = rsqrtf(s2 * (1.f / 1024.f) - mu * mu + 1e-5f);
      if (tid < 256) {
        int e = h * 256 + tid;
        float y = fmaxf((qrow[e] - mu) * rs * p.qg[e] + p.qbt[e], 0.f);
        qn[tid] = y;
        stsc(&p.xip[(size_t)b * 3072 + e], packsplit(y));
      }
      __syncthreads();
      // scores over slots 0..i; scale = 1/(16*0.1) = 0.625
      for (int s = wv; s <= i; s += 8) {
        const float* kp = p.keys + ((size_t)s * 32 + b) * 1024 + h * 256 + lane * 4;
        float kx = ldscf(kp), ky = ldscf(kp + 1), kz = ldscf(kp + 2), kw = ldscf(kp + 3);
        float pd = qn[lane * 4] * kx + qn[lane * 4 + 1] * ky +
                   qn[lane * 4 + 2] * kz + qn[lane * 4 + 3] * kw;
        pd = wred_add(pd);
        if (lane == 0) sc[s] = pd * 0.625f;
      }
      __syncthreads();
      float mx = (tid <= i) ? sc[tid] : -1e30f;
      mx = bred_max(mx, red, tid);
      float sum = 0.f;
      if (tid <= i) { float e = expf(sc[tid] - mx); sc[tid] = e; sum = e; }
      sum = bred_add(sum, red, tid);
      float inv = 1.f / sum;
      {
        float acc = 0.f;
        int d = tid & 255, half = tid >> 8;
        const float* vp = p.vals + (size_t)b * 1024 + h * 256 + d;
#pragma unroll 4
        for (int s = half; s <= i; s += 2) acc += sc[s] * ldscf(vp + (size_t)s * 32768);
        pv[tid] = acc;
      }
      __syncthreads();
      if (tid < 256) {
        float val = (pv[tid] + pv[tid + 256]) * inv;
        stsc(&p.xip[(size_t)b * 3072 + 1024 + h * 256 + tid], packsplit(val));
      }
    }
    gpost(flags, blk, base + 3u);

    // ---- P3: int2 (q+attn half), all 256 blocks ----
    {
      gwait(flags, 0, 0, base + 3u, 0);
      int kc = blk >> 5;               // 0..7, K-chunk 256
      stageA<8>(p.xip, 3072, kc * 256, sAh, sAl, tid);
      int nt = (blk & 31) * 8 + wv;    // 0..255
      floatx4 c0, c1;
      mm_lds(sAh, sAl, p.iwh, p.iwl, 4096, nt * 16, 1024 + kc * 256, 8, lane, c0, c1);
      store_part_sc(p.ip2 + (size_t)kc * 32 * 4096, 4096, nt, lane, c0, c1);
    }
    gpost(flags, blk, base + 4u);

    // ---- P4: LN-int (blocks 0..31) ----
    if (blk < 32) {
      gwait(flags, 0, 0, 0, base + 4u);
      int b = blk;
      float xs[8], s1 = 0.f, s2 = 0.f;
#pragma unroll
      for (int j = 0; j < 8; ++j) {
        int e = tid + j * 512;
        size_t o = (size_t)b * 4096 + e;
        float x = ((ldscf(&p.ip1[o]) + ldscf(&p.ip1[131072 + o])) +
                   (ldscf(&p.ip1[262144 + o]) + ldscf(&p.ip1[393216 + o]))) +
                  ((ldscf(&p.ip2[o]) + ldscf(&p.ip2[131072 + o])) +
                   (ldscf(&p.ip2[262144 + o]) + ldscf(&p.ip2[393216 + o]))) +
                  ((ldscf(&p.ip2[524288 + o]) + ldscf(&p.ip2[655360 + o])) +
                   (ldscf(&p.ip2[786432 + o]) + ldscf(&p.ip2[917504 + o]))) + p.ib[e];
        xs[j] = x; s1 += x; s2 += x * x;
      }
      s1 = bred_add(s1, red, tid);
      s2 = bred_add(s2, red, tid);
      float mu = s1 * (1.f / 4096.f);
      float rs = rsqrtf(s2 * (1.f / 4096.f) - mu * mu + 1e-5f);
#pragma unroll
      for (int j = 0; j < 8; ++j) {
        int e = tid + j * 512;
        float y = fmaxf((xs[j] - mu) * rs * p.ig[e] + p.ibt[e], 0.f);
        stsc(&p.interp[(size_t)b * 4096 + e], packsplit(y));
      }
    }
    gpost(flags, blk, base + 5u);

    // ---- P5: fin-GEMM (1536 wave-tasks over all 256 blocks, wv<6) ----
    {
      gwait(flags, base + 5u, 0, 0, 0);
      int kc = blk >> 5;               // 0..7, K-chunk 512
      stageA<9>(p.interp, 4096, kc * 512, sAh, sAl, tid);
      if (wv < 6) {
        int nt = (blk & 31) * 6 + wv;  // 0..191
        floatx4 c0, c1;
        mm_lds(sAh, sAl, p.fwh, p.fwl, 4096, nt * 16, kc * 512, 16, lane, c0, c1);
        store_part_sc(p.finpart + (size_t)kc * 32 * 3072, 3072, nt, lane, c0, c1);
      }
    }
    gpost(flags, blk, base + 6u);

    // ---- P6: merge fin + LN; keys/vals slot i+1, hidden -> xi & states ----
    if (blk < 32) {
      gwait(flags, 0, 0, 0, base + 6u);
      int b = blk;
      float xs[6], s1 = 0.f, s2 = 0.f;
#pragma unroll
      for (int j = 0; j < 6; ++j) {
        int e = tid + j * 512;
        size_t o = (size_t)b * 3072 + e;
        float x = ((ldscf(&p.finpart[o]) + ldscf(&p.finpart[98304 + o])) +
                   (ldscf(&p.finpart[196608 + o]) + ldscf(&p.finpart[294912 + o]))) +
                  ((ldscf(&p.finpart[393216 + o]) + ldscf(&p.finpart[491520 + o])) +
                   (ldscf(&p.finpart[589824 + o]) + ldscf(&p.finpart[688128 + o]))) + p.fb[e];
        xs[j] = x; s1 += x; s2 += x * x;
      }
      s1 = bred_add(s1, red, tid);
      s2 = bred_add(s2, red, tid);
      float mu = s1 * (1.f / 3072.f);
      float rs = rsqrtf(s2 * (1.f / 3072.f) - mu * mu + 1e-5f);
#pragma unroll
      for (int j = 0; j < 6; ++j) {
        int e = tid + j * 512;
        float y = fmaxf((xs[j] - mu) * rs * p.fg[e] + p.fbt[e], 0.f);
        if (j < 2) {
          stscf(&p.keys[((size_t)(i + 1) * 32 + b) * 1024 + e], y);
        } else if (j < 4) {
          stscf(&p.vals[((size_t)(i + 1) * 32 + b) * 1024 + (e - 1024)], y);
        } else {
          int d = e - 2048;
          stsc(&p.xip[(size_t)b * 3072 + 2048 + d], packsplit(y));
          p.states[((size_t)i * 32 + b) * 1024 + d] = f2bf(y);  // normal store; read post-boundary
        }
      }
    }
    gpost(flags, blk, base + 7u);
  }
}

// ---------------- decoder GEMM: logits = states @ dec_w^T + dec_b ----------------
__global__ void __launch_bounds__(256) dec_gemm(const u16* __restrict__ Sm,
                                                const u16* __restrict__ W,
                                                const float* __restrict__ Wb,
                                                float* __restrict__ out) {
  __shared__ u16 As[2][128 * 40];
  __shared__ u16 Bs[2][128 * 40];
  int bid = blockIdx.x;                      // 16000 % 8 == 0
  int swz = (bid & 7) * 2000 + (bid >> 3);
  int mt = swz / 250, nt = swz - mt * 250;
  const int tid = threadIdx.x;
  const int lane = tid & 63, wvi = tid >> 6;
  const int wm = wvi >> 1, wn = wvi & 1;
  const int fr = lane & 15, fg = lane >> 4;

  const int r0 = tid >> 2, k0 = (tid & 3) * 8;
  const u16* pa0 = Sm + (size_t)(mt * 128 + r0) * 1024 + k0;
  const u16* pa1 = pa0 + (size_t)64 * 1024;
  const u16* pb0 = W + (size_t)(nt * 128 + r0) * 1024 + k0;
  const u16* pb1 = pb0 + (size_t)64 * 1024;
  const int da0 = r0 * 40 + k0, da1 = (r0 + 64) * 40 + k0;

  floatx4 acc[4][4];
#pragma unroll
  for (int i = 0; i < 4; ++i)
#pragma unroll
    for (int j = 0; j < 4; ++j) acc[i][j] = floatx4{0.f, 0.f, 0.f, 0.f};

  uint4 ra0 = *(const uint4*)pa0, ra1 = *(const uint4*)pa1;
  uint4 rb0 = *(const uint4*)pb0, rb1 = *(const uint4*)pb1;
  *(uint4*)&As[0][da0] = ra0; *(uint4*)&As[0][da1] = ra1;
  *(uint4*)&Bs[0][da0] = rb0; *(uint4*)&Bs[0][da1] = rb1;
  __syncthreads();

  for (int kt = 0; kt < 32; ++kt) {
    const int cur = kt & 1;
    if (kt < 31) {
      const int off = (kt + 1) * 32;
      ra0 = *(const uint4*)(pa0 + off); ra1 = *(const uint4*)(pa1 + off);
      rb0 = *(const uint4*)(pb0 + off); rb1 = *(const uint4*)(pb1 + off);
    }
    bf16x8 af[4], bfv[4];
#pragma unroll
    for (int i = 0; i < 4; ++i) {
      af[i]  = *(const bf16x8*)&As[cur][(wm * 64 + i * 16 + fr) * 40 + fg * 8];
      bfv[i] = *(const bf16x8*)&Bs[cur][(wn * 64 + i * 16 + fr) * 40 + fg * 8];
    }
#pragma unroll
    for (int i = 0; i < 4; ++i)
#pragma unroll
      for (int j = 0; j < 4; ++j)
        acc[i][j] = __builtin_amdgcn_mfma_f32_16x16x32_bf16(af[i], bfv[j], acc[i][j], 0, 0, 0);
    if (kt < 31) {
      *(uint4*)&As[cur ^ 1][da0] = ra0; *(uint4*)&As[cur ^ 1][da1] = ra1;
      *(uint4*)&Bs[cur ^ 1][da0] = rb0; *(uint4*)&Bs[cur ^ 1][da1] = rb1;
    }
    __syncthreads();
  }

#pragma unroll
  for (int i = 0; i < 4; ++i)
#pragma unroll
    for (int j = 0; j < 4; ++j) {
      int col = nt * 128 + wn * 64 + j * 16 + fr;
      float bias = Wb[col];
#pragma unroll
      for (int r = 0; r < 4; ++r) {
        int row = mt * 128 + wm * 64 + i * 16 + fg * 4 + r;
        out[(size_t)row * 32000 + col] = acc[i][j][r] + bias;
      }
    }
}

extern "C" void kernel_launch(void* const* d_in, const int* in_sizes, int n_in,
                              void* d_out, int out_size, void* d_ws, size_t ws_size,
                              hipStream_t stream) {
  (void)in_sizes; (void)n_in; (void)out_size; (void)ws_size;
  char* ws = (char*)d_ws;
  size_t off = 0;
  auto carve = [&](size_t bytes) {
    void* pp = ws + off;
    off += (bytes + 255) & ~(size_t)255;
    return pp;
  };
  u16* qwh       = (u16*)carve((size_t)1024 * 2048 * 2);
  u16* qwl       = (u16*)carve((size_t)1024 * 2048 * 2);
  u16* iwh       = (u16*)carve((size_t)4096 * 4096 * 2);
  u16* iwl       = (u16*)carve((size_t)4096 * 4096 * 2);
  u16* fwh       = (u16*)carve((size_t)3072 * 4096 * 2);
  u16* fwl       = (u16*)carve((size_t)3072 * 4096 * 2);
  u32* ebp       = (u32*)carve((size_t)2 * 32 * 1024 * 4);
  u32* xip       = (u32*)carve((size_t)32 * 3072 * 4);
  u32* interp    = (u32*)carve((size_t)32 * 4096 * 4);
  float* qpart   = (float*)carve((size_t)8 * 32 * 1024 * 4);
  float* ip1     = (float*)carve((size_t)4 * 32 * 4096 * 4);
  float* ip2     = (float*)carve((size_t)8 * 32 * 4096 * 4);
  float* finpart = (float*)carve((size_t)8 * 32 * 3072 * 4);
  float* keysF   = (float*)carve((size_t)257 * 32 * 1024 * 4);
  float* valsF   = (float*)carve((size_t)257 * 32 * 1024 * 4);
  u16* states    = (u16*)carve((size_t)256 * 32 * 1024 * 2);
  u32* flags     = (u32*)carve((size_t)1024);
  // dec_w bf16 reuses the then-dead q/int weight region after the RNN.
  u16* dw_bf = (u16*)ws;

  hipMemsetAsync(flags, 0, 1024, stream);

  // weight hi/lo splits
  cvt_split<<<dim3(512), dim3(256), 0, stream>>>((const float*)d_in[2], qwh, qwl, 1024 * 2048 / 4);
  cvt_split<<<dim3(2048), dim3(256), 0, stream>>>((const float*)d_in[6], iwh, iwl, 4096 * 4096 / 4);
  cvt_split<<<dim3(2048), dim3(256), 0, stream>>>((const float*)d_in[10], fwh, fwl, 3072 * 4096 / 4);

  Prm prm;
  prm.obs = (const int*)d_in[0];
  prm.emb = (const float*)d_in[1];
  prm.qwh = qwh; prm.qwl = qwl;
  prm.qb  = (const float*)d_in[3];
  prm.qg  = (const float*)d_in[4];
  prm.qbt = (const float*)d_in[5];
  prm.iwh = iwh; prm.iwl = iwl;
  prm.ib  = (const float*)d_in[7];
  prm.ig  = (const float*)d_in[8];
  prm.ibt = (const float*)d_in[9];
  prm.fwh = fwh; prm.fwl = fwl;
  prm.fb  = (const float*)d_in[11];
  prm.fg  = (const float*)d_in[12];
  prm.fbt = (const float*)d_in[13];
  prm.hid0 = (const float*)d_in[16];
  prm.key0 = (const float*)d_in[17];
  prm.val0 = (const float*)d_in[18];
  prm.ebp = ebp; prm.xip = xip; prm.interp = interp;
  prm.states = states; prm.keys = keysF; prm.vals = valsF;
  prm.qpart = qpart; prm.ip1 = ip1; prm.ip2 = ip2; prm.finpart = finpart;
  prm.flags = flags;

  void* args[] = { &prm };
  hipLaunchCooperativeKernel(rnn_kernel, dim3(256), dim3(512), args, 0, stream);

  // dec_w fp32 -> bf16 into reused region (q/int weights dead after RNN)
  cvt_bf16<<<dim3(4096), dim3(256), 0, stream>>>((const float*)d_in[14], dw_bf, 32000 * 1024 / 4);

  dec_gemm<<<dim3(16000), dim3(256), 0, stream>>>(
      states, dw_bf, (const float*)d_in[15], (float*)d_out);
}